// Round 9
// baseline (319.166 us; speedup 1.0000x reference)
//
#include <hip/hip_runtime.h>
#include <hip/hip_bf16.h>
#include <math.h>

// Problem constants: B=4, D=1024, N=2048, K=1024, fp32 in/out.
#define BB 4
#define DD 1024
#define NN 2048
#define KK 1024
#define NT128 16            // NN/128
#define NTRI 136            // 16*17/2 lower-triangular 128x128 tiles
#define TRI_ELEMS 16384     // 128*128

typedef __attribute__((ext_vector_type(4))) float f32x4;
typedef __attribute__((ext_vector_type(8))) short bfrag;

typedef __attribute__((address_space(1))) const unsigned int gu32;
typedef __attribute__((address_space(3))) unsigned int lu32;

// async global->LDS, 16B per lane; LDS dest = base + lane*16 (wave-uniform base)
__device__ __forceinline__ void async16(const void* g, void* l) {
  __builtin_amdgcn_global_load_lds((gu32*)g, (lu32*)l, 16, 0, 0);
}

__device__ __forceinline__ ushort f2b(float f) {  // fp32 -> bf16 RNE
  union { float f; unsigned u; } c; c.f = f;
  unsigned u = c.u + 0x7fffu + ((c.u >> 16) & 1u);
  return (ushort)(u >> 16);
}
__device__ __forceinline__ float b2f(ushort h) {
  union { unsigned u; float f; } c; c.u = ((unsigned)h) << 16;
  return c.f;
}

// ---------------------------------------------------------------------------
// prep: merged input transform, grid (64, 32, 6), block (32,8).
//  z<4 : x [b=z][d][n] fp32 -> x_hi (bf16 same layout), xT hi/lo ([b][n][d])
//        float4 loads + ushort4 stores (G13), one pass per 32x32 tile (R8).
//  z>=4: weight w = (z-4)*2 + (bx>>5): W (K x D, [k][d]) -> WT [d][k] bf16
//        (WQ, WK split hi+lo; WV, WO hi only). R9: same one-pass float4
//        restructure as the x-branch (2-way LDS aliasing in transpose = free).
// ---------------------------------------------------------------------------
__global__ __launch_bounds__(256) void prep(
    const float* __restrict__ x,
    const float* __restrict__ WQ, const float* __restrict__ WK,
    const float* __restrict__ WV, const float* __restrict__ WO,
    ushort* __restrict__ xhi, ushort* __restrict__ xTh, ushort* __restrict__ xTl,
    ushort* __restrict__ qh, ushort* __restrict__ ql,
    ushort* __restrict__ kh, ushort* __restrict__ kl_,
    ushort* __restrict__ vh, ushort* __restrict__ oh) {
  const int z = blockIdx.z;
  const int tx = threadIdx.x, ty = threadIdx.y;
  __shared__ float tile[32][33];
  const int tid = ty * 32 + tx;
  if (z < 4) {
    const int b = z;
    const int n0 = blockIdx.x * 32, d0 = blockIdx.y * 32;
    const float* xb = x + (long)b * DD * NN;
    ushort* xhb = xhi + (long)b * DD * NN;
    // load phase: 256 threads cover 32 d-rows x 8 float4 (32 n-cols)
    const int dl = tid >> 3, c4 = (tid & 7) * 4;
    const float4 v4 = *(const float4*)&xb[(long)(d0 + dl) * NN + n0 + c4];
    tile[dl][c4 + 0] = v4.x; tile[dl][c4 + 1] = v4.y;
    tile[dl][c4 + 2] = v4.z; tile[dl][c4 + 3] = v4.w;
    ushort4 h4;
    h4.x = f2b(v4.x); h4.y = f2b(v4.y); h4.z = f2b(v4.z); h4.w = f2b(v4.w);
    *(ushort4*)&xhb[(long)(d0 + dl) * NN + n0 + c4] = h4;
    __syncthreads();
    // transpose phase: each thread emits 4 consecutive d for one n (ushort4)
    const int nl = tid >> 3, d4 = (tid & 7) * 4;
    const float w0 = tile[d4 + 0][nl], w1 = tile[d4 + 1][nl];
    const float w2 = tile[d4 + 2][nl], w3 = tile[d4 + 3][nl];
    ushort4 hh, ll;
    hh.x = f2b(w0); ll.x = f2b(w0 - b2f(hh.x));
    hh.y = f2b(w1); ll.y = f2b(w1 - b2f(hh.y));
    hh.z = f2b(w2); ll.z = f2b(w2 - b2f(hh.z));
    hh.w = f2b(w3); ll.w = f2b(w3 - b2f(hh.w));
    const long o = (long)b * NN * DD + (long)(n0 + nl) * DD + d0 + d4;
    *(ushort4*)&xTh[o] = hh;
    *(ushort4*)&xTl[o] = ll;
  } else {
    const int w = (z - 4) * 2 + (blockIdx.x >> 5);
    const float* W = (w == 0) ? WQ : (w == 1) ? WK : (w == 2) ? WV : WO;
    ushort* Th = (w == 0) ? qh : (w == 1) ? kh : (w == 2) ? vh : oh;
    ushort* Tl = (w == 0) ? ql : (w == 1) ? kl_ : nullptr;
    const int k0 = (blockIdx.x & 31) * 32, d0 = blockIdx.y * 32;
    // load phase: 32 k-rows x 8 float4 (32 d-cols)
    const int kl = tid >> 3, c4 = (tid & 7) * 4;
    const float4 v4 = *(const float4*)&W[(long)(k0 + kl) * DD + d0 + c4];
    tile[kl][c4 + 0] = v4.x; tile[kl][c4 + 1] = v4.y;
    tile[kl][c4 + 2] = v4.z; tile[kl][c4 + 3] = v4.w;
    __syncthreads();
    // transpose phase: each thread emits 4 consecutive k for one d (ushort4)
    const int dl = tid >> 3, k4 = (tid & 7) * 4;
    const float w0 = tile[k4 + 0][dl], w1 = tile[k4 + 1][dl];
    const float w2 = tile[k4 + 2][dl], w3 = tile[k4 + 3][dl];
    ushort4 hh;
    hh.x = f2b(w0); hh.y = f2b(w1); hh.z = f2b(w2); hh.w = f2b(w3);
    const long o = (long)(d0 + dl) * KK + k0 + k4;
    *(ushort4*)&Th[o] = hh;
    if (Tl) {
      ushort4 ll;
      ll.x = f2b(w0 - b2f(hh.x)); ll.y = f2b(w1 - b2f(hh.y));
      ll.z = f2b(w2 - b2f(hh.z)); ll.w = f2b(w3 - b2f(hh.w));
      *(ushort4*)&Tl[o] = ll;
    }
  }
}

// ---------------------------------------------------------------------------
// Merged weight-product GEMM, 64x64 tiles, BK=32, 512 blocks:
//   id<256 : Mqk[m,n] = sum_k wqT[m,k] wkT[n,k]  (split 3-MFMA, split store)
//   id>=256: Mov[m,n] = sum_k woT[m,k] wvT[n,k]  (plain bf16)
// R9: R4 recipe schedule (dbuf 2x16KB = 32KB; STAGE(t+1) issued BEFORE
// compute; ONE vmcnt(0)+barrier per tile AFTER the MFMAs; setprio cluster)
// replacing the old single-buffer 2-syncthreads drain. LDS layout and the
// (r16>>1)&3 swizzle unchanged.
// ---------------------------------------------------------------------------
__global__ __launch_bounds__(256) void gemm_w(
    const ushort* __restrict__ qh, const ushort* __restrict__ ql,
    const ushort* __restrict__ kh, const ushort* __restrict__ kl_,
    const ushort* __restrict__ vh, const ushort* __restrict__ oh,
    ushort* __restrict__ mqk_h, ushort* __restrict__ mqk_l,
    ushort* __restrict__ mov_h) {
  extern __shared__ ushort smem[];   // 2 x 8192 ushorts (Ah|Al|Bh|Bl @2048 ea)

  const int id = blockIdx.x;
  const int half = id >> 8;                  // 0 = Mqk (split), 1 = Mov (plain)
  const int t = id & 255;
  const int m0 = (t >> 4) * 64, n0 = (t & 15) * 64;
  const ushort* A_h = half ? oh : qh;
  const ushort* B_h = half ? vh : kh;

  const int tid = threadIdx.x;
  const int lane = tid & 63, wave = tid >> 6;
  const int wm = (wave & 1) * 32, wn = (wave >> 1) * 32;
  const int r16 = lane & 15, quad = lane >> 4;
  const int kc = ((lane & 3) ^ ((lane >> 3) & 3)) * 8;   // swizzled k-chunk
  const int srow = lane >> 2;

  f32x4 acc[2][2];
#pragma unroll
  for (int i = 0; i < 2; ++i)
#pragma unroll
    for (int j = 0; j < 2; ++j) acc[i][j] = (f32x4){0.f, 0.f, 0.f, 0.f};

  auto STAGE = [&](int db, int k0) {
    ushort* s = smem + db * 8192;
    const int row = wave * 16 + srow;
    const long aoff = (long)(m0 + row) * KK + k0 + kc;
    const long boff = (long)(n0 + row) * KK + k0 + kc;
    async16(A_h + aoff, s + wave * 512);
    async16(B_h + boff, s + 4096 + wave * 512);
    if (half == 0) {
      async16(ql + aoff, s + 2048 + wave * 512);
      async16(kl_ + boff, s + 6144 + wave * 512);
    }
  };

  const int T = KK >> 5;                     // 32 K-tiles
  STAGE(0, 0);
  asm volatile("s_waitcnt vmcnt(0)" ::: "memory");
  __builtin_amdgcn_s_barrier();
  __builtin_amdgcn_sched_barrier(0);

  for (int kt = 0; kt < T; ++kt) {
    const int cur = kt & 1;
    if (kt + 1 < T) STAGE(cur ^ 1, (kt + 1) << 5);   // issue BEFORE compute
    const ushort* s = smem + cur * 8192;

    const int sw = (r16 >> 1) & 3;
    bfrag ah[2], bh[2], al[2], bl[2];
#pragma unroll
    for (int t2 = 0; t2 < 2; ++t2) {
      ah[t2] = *(const bfrag*)&s[(wm + t2 * 16 + r16) * 32 + (quad ^ sw) * 8];
      bh[t2] = *(const bfrag*)&s[4096 + (wn + t2 * 16 + r16) * 32 + (quad ^ sw) * 8];
      if (half == 0) {
        al[t2] = *(const bfrag*)&s[2048 + (wm + t2 * 16 + r16) * 32 + (quad ^ sw) * 8];
        bl[t2] = *(const bfrag*)&s[6144 + (wn + t2 * 16 + r16) * 32 + (quad ^ sw) * 8];
      }
    }
    __builtin_amdgcn_s_setprio(1);
#pragma unroll
    for (int mt = 0; mt < 2; ++mt)
#pragma unroll
      for (int nt = 0; nt < 2; ++nt) {
        acc[mt][nt] = __builtin_amdgcn_mfma_f32_16x16x32_bf16(ah[mt], bh[nt], acc[mt][nt], 0, 0, 0);
        if (half == 0) {
          acc[mt][nt] = __builtin_amdgcn_mfma_f32_16x16x32_bf16(ah[mt], bl[nt], acc[mt][nt], 0, 0, 0);
          acc[mt][nt] = __builtin_amdgcn_mfma_f32_16x16x32_bf16(al[mt], bh[nt], acc[mt][nt], 0, 0, 0);
        }
      }
    __builtin_amdgcn_s_setprio(0);

    __builtin_amdgcn_sched_barrier(0);
    asm volatile("s_waitcnt vmcnt(0)" ::: "memory");   // kt+1 loads landed
    __builtin_amdgcn_s_barrier();                      // buf[cur^1] ready
    __builtin_amdgcn_sched_barrier(0);
  }

#pragma unroll
  for (int mt = 0; mt < 2; ++mt)
#pragma unroll
    for (int nt = 0; nt < 2; ++nt)
#pragma unroll
      for (int reg = 0; reg < 4; ++reg) {
        const int ml = wm + mt * 16 + quad * 4 + reg;
        const int nl = wn + nt * 16 + r16;
        const float v = acc[mt][nt][reg];
        const long o = (long)(m0 + ml) * DD + n0 + nl;
        if (half == 0) {
          const ushort h = f2b(v);
          mqk_h[o] = h;
          mqk_l[o] = f2b(v - b2f(h));
        } else {
          mov_h[o] = f2b(v);
        }
      }
}

// ---------------------------------------------------------------------------
// bf16 MFMA GEMM (R4-exact, best measured): 128x128 block tile, 4 waves
// (2x2) of 64x64, recipe dbuf schedule (STAGE(t+1) issued BEFORE compute,
// ONE vmcnt(0)+barrier per tile AFTER the MFMAs), ^(row&7) chunk swizzle
// realized via pre-swizzled global source (0 conflicts, R2-R5 measured).
// SPLIT=1: BK=32, hi|lo packed per 128B row (chunks 0-3 = hi k, 4-7 = lo).
// SPLIT=0: BK=64, chunks = k-chunks.
// Fragment layouts (HW-verified, learn_hip m89):
//   A[m=lane&15][k=quad*8+j], B[n=lane&15][k=quad*8+j],
//   C/D: col=lane&15, row=quad*4+reg.
// TRIA : A staged from triangular tile layout; K limited to m0+128.
// SWIZ : XCD-locality block mapping (assumes xcd = blockIdx.x % 8):
//   1: 512 blocks, (b, m0)=P, n0: M=16 tiles, N=8 tiles
//   2: 544 blocks (logits tri), g=(blk&7)*68+(blk>>3); b=g/136, t=g%136
//   3: 512 blocks, causal-balanced: XCD x owns mtiles {x, 15-x}
//   4: 512 blocks, swapped roles (M=8 d-tiles, N=16 i-tiles)
// STORE 0: split bf16 (C0=hi, C1=lo); 1: tri fp32; 2: bf16; 3: fp32 + Res.
// ---------------------------------------------------------------------------
template <int SPLIT, int TRIA, int STORE, int SWIZ>
__global__ __launch_bounds__(256) void gemm_mfma(
    const ushort* __restrict__ Ah, const ushort* __restrict__ Al,
    const ushort* __restrict__ Bh, const ushort* __restrict__ Bl,
    void* __restrict__ C0, void* __restrict__ C1, const float* __restrict__ Res,
    int K, int lda, int ldb, int ldc,
    long bA, long bB, long bC, long bR) {
  extern __shared__ ushort smem[];   // 2 x 16384 ushorts (sA 8192 | sB 8192)

  int b, m0, n0, tiC = 0;
  if (SWIZ == 2) {
    const int g = (blockIdx.x & 7) * 68 + (blockIdx.x >> 3);
    b = g / NTRI;
    int t = g - b * NTRI;
    int ti = 0;
    while ((ti + 1) * (ti + 2) / 2 <= t) ++ti;
    const int tj = t - ti * (ti + 1) / 2;
    m0 = ti * 128; n0 = tj * 128; tiC = t;
  } else if (SWIZ == 1) {
    const int g = (blockIdx.x & 7) * 64 + (blockIdx.x >> 3);
    const int P = g >> 3;
    b = P >> 4;
    m0 = (P & 15) * 128;
    n0 = (g & 7) * 128;
  } else if (SWIZ == 3) {
    const int xcd = blockIdx.x & 7;
    const int idx = blockIdx.x >> 3;      // [0,64)
    const int q = idx >> 3;               // [0,8)
    b = q >> 1;
    const int mt_ = (q & 1) ? (15 - xcd) : xcd;
    m0 = mt_ * 128;
    n0 = (idx & 7) * 128;
  } else {  // SWIZ == 4
    const int g = (blockIdx.x & 7) * 64 + (blockIdx.x >> 3);
    const int P = g >> 3;
    b = P >> 4;
    n0 = (P & 15) * 128;
    m0 = (g & 7) * 128;
  }
  const int kmax = TRIA ? (m0 + 128) : K;
  int triA0 = 0;
  if (TRIA) { const int ti = m0 >> 7; triA0 = ti * (ti + 1) / 2; }

  const ushort* A_h = Ah + (long)b * bA;
  const ushort* B_h = Bh + (long)b * bB;
  const ushort* A_l = SPLIT ? Al + (long)b * bA : nullptr;
  const ushort* B_l = SPLIT ? Bl + (long)b * bB : nullptr;

  const int tid = threadIdx.x;
  const int lane = tid & 63, wave = tid >> 6;
  const int wm = (wave & 1) * 64, wn = (wave >> 1) * 64;
  const int r16 = lane & 15, quad = lane >> 4;
  const int rk = r16 & 7;

  // staging lane mapping: 8 rows x 8 phys chunks per async16 (1KB)
  const int lrow = lane >> 3;                  // row within 8-row segment
  const int lc = (lane & 7) ^ lrow;            // logical chunk = phys ^ row&7
  // SPLIT: logical chunks 0-3 = hi k-chunks, 4-7 = lo k-chunks
  const int lckS = (lc & 3) * 8;
  const bool lo_src = lc >= 4;
  // plain: logical chunk = k-chunk of BK=64
  const int kcP = lc * 8;

  f32x4 acc[4][4];
#pragma unroll
  for (int i = 0; i < 4; ++i)
#pragma unroll
    for (int j = 0; j < 4; ++j) acc[i][j] = (f32x4){0.f, 0.f, 0.f, 0.f};

  auto STAGE = [&](int db, int t) {
    ushort* dst = smem + db * 16384;
    if (SPLIT) {
      const int k0 = t << 5;
#pragma unroll
      for (int s = 0; s < 4; ++s) {
        const int seg = wave * 4 + s;          // [0,16): 8-row group
        const int row = seg * 8 + lrow;        // [0,128)
        const ushort* baseA = lo_src ? A_l : A_h;
        const ushort* baseB = lo_src ? B_l : B_h;
        async16(baseA + (long)(m0 + row) * lda + k0 + lckS, dst + seg * 512);
        async16(baseB + (long)(n0 + row) * ldb + k0 + lckS, dst + 8192 + seg * 512);
      }
    } else {
      const int k0 = t << 6;
#pragma unroll
      for (int s = 0; s < 4; ++s) {
        const int seg = wave * 4 + s;
        const int row = seg * 8 + lrow;
        long aoff;
        if (TRIA)
          aoff = (long)(triA0 + (k0 >> 7)) * TRI_ELEMS + (long)row * 128 + (k0 & 127) + kcP;
        else
          aoff = (long)(m0 + row) * lda + k0 + kcP;
        async16(A_h + aoff, dst + seg * 512);
        async16(B_h + (long)(n0 + row) * ldb + k0 + kcP, dst + 8192 + seg * 512);
      }
    }
  };

  const int T = kmax >> (SPLIT ? 5 : 6);
  STAGE(0, 0);
  asm volatile("s_waitcnt vmcnt(0)" ::: "memory");
  __builtin_amdgcn_s_barrier();
  __builtin_amdgcn_sched_barrier(0);

  for (int t = 0; t < T; ++t) {
    const int cur = t & 1;
    if (t + 1 < T) STAGE(cur ^ 1, t + 1);      // issue BEFORE compute
    const ushort* sA = smem + cur * 16384;
    const ushort* sB = sA + 8192;

    if (SPLIT) {
      bfrag ah[4], al[4], bh[4], bl[4];
#pragma unroll
      for (int f = 0; f < 4; ++f) {
        const int arow = (wm + f * 16 + r16) * 64;
        const int brow = (wn + f * 16 + r16) * 64;
        ah[f] = *(const bfrag*)&sA[arow + (quad ^ rk) * 8];
        al[f] = *(const bfrag*)&sA[arow + ((quad + 4) ^ rk) * 8];
        bh[f] = *(const bfrag*)&sB[brow + (quad ^ rk) * 8];
        bl[f] = *(const bfrag*)&sB[brow + ((quad + 4) ^ rk) * 8];
      }
      __builtin_amdgcn_s_setprio(1);
#pragma unroll
      for (int mt = 0; mt < 4; ++mt)
#pragma unroll
        for (int nt = 0; nt < 4; ++nt) {
          acc[mt][nt] = __builtin_amdgcn_mfma_f32_16x16x32_bf16(ah[mt], bh[nt], acc[mt][nt], 0, 0, 0);
          acc[mt][nt] = __builtin_amdgcn_mfma_f32_16x16x32_bf16(ah[mt], bl[nt], acc[mt][nt], 0, 0, 0);
          acc[mt][nt] = __builtin_amdgcn_mfma_f32_16x16x32_bf16(al[mt], bh[nt], acc[mt][nt], 0, 0, 0);
        }
      __builtin_amdgcn_s_setprio(0);
    } else {
#pragma unroll
      for (int ksub = 0; ksub < 2; ++ksub) {
        const int ch = ((ksub * 4 + quad) ^ rk) * 8;     // physical chunk
        bfrag a4[4], b4[4];
#pragma unroll
        for (int f = 0; f < 4; ++f) {
          a4[f] = *(const bfrag*)&sA[(wm + f * 16 + r16) * 64 + ch];
          b4[f] = *(const bfrag*)&sB[(wn + f * 16 + r16) * 64 + ch];
        }
        __builtin_amdgcn_s_setprio(1);
#pragma unroll
        for (int mt = 0; mt < 4; ++mt)
#pragma unroll
          for (int nt = 0; nt < 4; ++nt)
            acc[mt][nt] = __builtin_amdgcn_mfma_f32_16x16x32_bf16(a4[mt], b4[nt], acc[mt][nt], 0, 0, 0);
        __builtin_amdgcn_s_setprio(0);
      }
    }

    __builtin_amdgcn_sched_barrier(0);
    asm volatile("s_waitcnt vmcnt(0)" ::: "memory");   // t+1 loads landed
    __builtin_amdgcn_s_barrier();                      // buf[cur^1] ready
    __builtin_amdgcn_sched_barrier(0);
  }

  // epilogue
#pragma unroll
  for (int mt = 0; mt < 4; ++mt)
#pragma unroll
    for (int nt = 0; nt < 4; ++nt)
#pragma unroll
      for (int reg = 0; reg < 4; ++reg) {
        const int ml = wm + mt * 16 + quad * 4 + reg;
        const int nl = wn + nt * 16 + r16;
        const float v = acc[mt][nt][reg];
        if (STORE == 0) {
          ushort* Ch = (ushort*)C0 + (long)b * bC;
          ushort* Cl = (ushort*)C1 + (long)b * bC;
          const long o = (long)(m0 + ml) * ldc + n0 + nl;
          const ushort h = f2b(v);
          Ch[o] = h;
          Cl[o] = f2b(v - b2f(h));
        } else if (STORE == 1) {
          float* C = (float*)C0 + (long)b * bC + (long)tiC * TRI_ELEMS;
          C[ml * 128 + nl] = v;
        } else if (STORE == 2) {
          ushort* C = (ushort*)C0 + (long)b * bC;
          C[(long)(m0 + ml) * ldc + n0 + nl] = f2b(v);
        } else {
          float* C = (float*)C0 + (long)b * bC;
          const float* R = Res + (long)b * bR;
          const long o = (long)(m0 + ml) * ldc + n0 + nl;
          C[o] = R[o] + v;
        }
      }
}

// ---------------------------------------------------------------------------
// Causal softmax over triangular-tiled logits. One block per row (b, i).
// float4 logit loads + ushort4 A-stores (G13, R8). Cols in [len, tot) within
// stored tiles hold finite garbage (step 3 writes full 128x128 tiles for
// jt<=ti) -> safe to load, masked with -INF / zero.
// ---------------------------------------------------------------------------
__global__ __launch_bounds__(256) void softmax_tri(
    const float* __restrict__ L, ushort* __restrict__ Aout) {
  const int row = blockIdx.x;
  const int b = row >> 11, i = row & (NN - 1);
  const int ti = i >> 7, ml = i & 127;
  const long base = (long)b * ((long)NTRI * TRI_ELEMS);
  const int trib = ti * (ti + 1) / 2;
  const int len = i + 1;
  const int tot = (ti + 1) * 128;
  const int tid = threadIdx.x;
  __shared__ float red[256];
  float vv[8];
  float m = -INFINITY;
#pragma unroll
  for (int u = 0; u < 2; ++u) {
    const int j = (tid + u * 256) * 4;
    if (j < tot) {
      const long o = base + (long)(trib + (j >> 7)) * TRI_ELEMS + ml * 128 + (j & 127);
      const float4 v = *(const float4*)&L[o];
      vv[u * 4 + 0] = v.x; vv[u * 4 + 1] = v.y;
      vv[u * 4 + 2] = v.z; vv[u * 4 + 3] = v.w;
#pragma unroll
      for (int e = 0; e < 4; ++e)
        if (j + e < len) m = fmaxf(m, vv[u * 4 + e]);
    }
  }
  red[tid] = m; __syncthreads();
  for (int s = 128; s; s >>= 1) { if (tid < s) red[tid] = fmaxf(red[tid], red[tid + s]); __syncthreads(); }
  m = red[0]; __syncthreads();
  float sum = 0.f;
#pragma unroll
  for (int u = 0; u < 2; ++u) {
    const int j = (tid + u * 256) * 4;
#pragma unroll
    for (int e = 0; e < 4; ++e) {
      if (j + e < len) { const float ex = __expf(vv[u * 4 + e] - m); vv[u * 4 + e] = ex; sum += ex; }
      else vv[u * 4 + e] = 0.f;
    }
  }
  red[tid] = sum; __syncthreads();
  for (int s = 128; s; s >>= 1) { if (tid < s) red[tid] += red[tid + s]; __syncthreads(); }
  const float inv = 1.f / red[0];
#pragma unroll
  for (int u = 0; u < 2; ++u) {
    const int j = (tid + u * 256) * 4;
    if (j < tot) {
      ushort4 o4;
      o4.x = (j + 0 < len) ? f2b(vv[u * 4 + 0] * inv) : (ushort)0;
      o4.y = (j + 1 < len) ? f2b(vv[u * 4 + 1] * inv) : (ushort)0;
      o4.z = (j + 2 < len) ? f2b(vv[u * 4 + 2] * inv) : (ushort)0;
      o4.w = (j + 3 < len) ? f2b(vv[u * 4 + 3] * inv) : (ushort)0;
      const long o = base + (long)(trib + (j >> 7)) * TRI_ELEMS + ml * 128 + (j & 127);
      *(ushort4*)&Aout[o] = o4;
    }
  }
}

// ---------------------------------------------------------------------------
// Pipeline (all MFMA operands k-contiguous by construction):
//  0. prep: x -> x_hi, xT hi/lo; W_Q..W_O -> WT [d][k] bf16     (1 dispatch)
//  1. gemm_w: Mqk (split) + Mov (plain) in one 512-block dispatch
//  2. tT[i,d] = sum_e xT[i,e] Mqk[d,e]      split, SWIZ=1, 512 blocks
//  3. logits[i,j] = sum_d xT[i,d] tT[j,d]   split, tri tiles, SWIZ=2, 544
//  4. A = causal softmax (bf16, tri layout, zero-padded diag tiles)
//  5. ctxT[i,e] = sum_{t<=i} A[i,t] x[e,t]  plain, causal K, SWIZ=3 (bal)
//  6. out[d,i] = x[d,i] + sum_e Mov[d,e] ctxT[i,e]   plain + res, SWIZ=4
// ---------------------------------------------------------------------------
extern "C" void kernel_launch(void* const* d_in, const int* in_sizes, int n_in,
                              void* d_out, int out_size, void* d_ws, size_t ws_size,
                              hipStream_t stream) {
  const float* x = (const float*)d_in[0];
  const float* WQ = (const float*)d_in[1];
  const float* WK = (const float*)d_in[2];
  const float* WV = (const float*)d_in[3];
  const float* WO = (const float*)d_in[4];
  float* out = (float*)d_out;

  const long XE = (long)BB * DD * NN;    // 8M elements
  const long WE = (long)DD * KK;         // 1M elements
  ushort* x_hi = (ushort*)d_ws;
  ushort* xTh = x_hi + XE;
  ushort* xTl = xTh + XE;
  ushort* wqT_h = xTl + XE;
  ushort* wqT_l = wqT_h + WE;
  ushort* wkT_h = wqT_l + WE;
  ushort* wkT_l = wkT_h + WE;
  ushort* wvT_h = wkT_l + WE;
  ushort* woT_h = wvT_h + WE;
  ushort* mqk_h = woT_h + WE;
  ushort* mqk_l = mqk_h + WE;
  ushort* mov_h = mqk_l + WE;
  ushort* tTh = mov_h + WE;
  ushort* tTl = tTh + XE;
  float* logits = (float*)(tTl + XE);    // B*NTRI*TRI_ELEMS fp32 (~35.7MB)
  ushort* A_tri = tTh;                   // overlays tT hi+lo (dead after step 3)
  ushort* ctxT = (ushort*)logits;        // overlays logits (dead after softmax)
  const long TRIB = (long)NTRI * TRI_ELEMS;
  const long XB = XE / BB;

  prep<<<dim3(64, 32, 6), dim3(32, 8), 0, stream>>>(
      x, WQ, WK, WV, WO, x_hi, xTh, xTl,
      wqT_h, wqT_l, wkT_h, wkT_l, wvT_h, woT_h);

  // Mqk (split) + Mov (plain), merged 64-tile dispatch, recipe dbuf 32KB
  gemm_w<<<dim3(512), 256, 32768, stream>>>(
      wqT_h, wqT_l, wkT_h, wkT_l, wvT_h, woT_h, mqk_h, mqk_l, mov_h);

  // tT = xT * Mqk^T (split, recipe dbuf BK=32, 64KB LDS, 2 blk/CU)
  gemm_mfma<1, 0, 0, 1><<<dim3(512), 256, 65536, stream>>>(
      xTh, xTl, mqk_h, mqk_l, tTh, tTl, nullptr,
      DD, DD, DD, DD, XB, 0, XB, 0);

  // logits (lower tri tiles, split recipe dbuf)
  gemm_mfma<1, 0, 1, 2><<<dim3(BB * NTRI), 256, 65536, stream>>>(
      xTh, xTl, tTh, tTl, logits, nullptr, nullptr,
      DD, DD, DD, 0, XB, XB, TRIB, 0);

  softmax_tri<<<dim3(BB * NN), 256, 0, stream>>>(logits, A_tri);

  // ctxT = A * x^T (tri A, causal K-limit, balanced XCD swizzle, dbuf)
  gemm_mfma<0, 1, 2, 3><<<dim3(512), 256, 65536, stream>>>(
      A_tri, nullptr, x_hi, nullptr, ctxT, nullptr, nullptr,
      NN, 0, NN, DD, TRIB, XB, XB, 0);

  // out = x + Mov * ctx (SWIZ=4: M=8 d-tiles, N=16 i-tiles, dbuf)
  gemm_mfma<0, 0, 3, 4><<<dim3(512), 256, 65536, stream>>>(
      mov_h, nullptr, ctxT, nullptr, out, nullptr, x,
      DD, DD, DD, NN, 0, XB, XB, XB);
}